// Round 9
// baseline (382.136 us; speedup 1.0000x reference)
//
#include <hip/hip_runtime.h>
#include <hip/hip_cooperative_groups.h>

namespace cg = cooperative_groups;

// Single cooperative kernel: phase 1 computes per-bin partition boundaries of
// both sorted arrays by bin-transition detection (streaming, no dependent-load
// chains); grid.sync(); phase 2 = per-bin LDS-bitmap mark + probe + contiguous
// output write. Fallback to the R8 two-kernel path if coop launch is refused.

typedef int   v4i __attribute__((ext_vector_type(4)));
typedef float v4f __attribute__((ext_vector_type(4)));

static constexpr int WORDS_PER_BLOCK = 128;            // 512 B LDS bitmap
static constexpr int SITES_PER_BLOCK = 4096;           // = 2^BIN_SHIFT
static constexpr int BIN_SHIFT       = 12;
static constexpr int GRID            = 2048;           // bins == blocks
static constexpr int BLOCK           = 256;

// ---- boundary detection by bin transitions (sorted input) ------------------
__device__ __forceinline__ void transitions(
    const int* __restrict__ x, int* __restrict__ bnd, int n, int t)
{
    const int s = t * 4;
    if (s >= n) return;
    int v[4];
    int cnt;
    if (s + 4 <= n) {
        v4i a = __builtin_nontemporal_load((const v4i*)(x + s));
        v[0] = a.x; v[1] = a.y; v[2] = a.z; v[3] = a.w;
        cnt = 4;
    } else {
        cnt = n - s;
        for (int j = 0; j < cnt; ++j) v[j] = x[s + j];
    }
    int pbin = (s == 0) ? -1 : (x[s - 1] >> BIN_SHIFT);
    for (int j = 0; j < cnt; ++j) {
        const int i = s + j;
        const int cbin = v[j] >> BIN_SHIFT;
        for (int b = pbin + 1; b <= cbin; ++b)
            __hip_atomic_store(&bnd[b], i, __ATOMIC_RELAXED, __HIP_MEMORY_SCOPE_AGENT);
        if (i == n - 1)
            for (int b = cbin + 1; b <= GRID; ++b)
                __hip_atomic_store(&bnd[b], n, __ATOMIC_RELAXED, __HIP_MEMORY_SCOPE_AGENT);
        pbin = cbin;
    }
}

// ---- per-bin mark + probe (R8-proven body) ---------------------------------
__device__ __forceinline__ void mark_and_probe(
    const int*   __restrict__ ss,
    const int*   __restrict__ sig,
    const int*   __restrict__ a2s,
    const float* __restrict__ sc,
    unsigned int* lbm,
    float*       __restrict__ rem,
    float*       __restrict__ avail,
    int e0, int e1, int p0, int p1, int siteBase, int n_clb)
{
    const int siteEnd = siteBase + SITES_PER_BLOCK;

    // mark: 8 entries/thread (4 NT vec4 loads in flight); strays outside the
    // bin's site range fail the range check (they belong to neighbor bins).
    const int mstart = e0 & ~3;
    for (int s = mstart + threadIdx.x * 8; s < e1; s += BLOCK * 8) {
        int av[8], gv[8];
        if (s + 8 <= n_clb) {
            v4i a0 = __builtin_nontemporal_load((const v4i*)(a2s + s));
            v4i a1 = __builtin_nontemporal_load((const v4i*)(a2s + s + 4));
            v4i g0 = __builtin_nontemporal_load((const v4i*)(sig + s));
            v4i g1 = __builtin_nontemporal_load((const v4i*)(sig + s + 4));
            av[0]=a0.x; av[1]=a0.y; av[2]=a0.z; av[3]=a0.w;
            av[4]=a1.x; av[5]=a1.y; av[6]=a1.z; av[7]=a1.w;
            gv[0]=g0.x; gv[1]=g0.y; gv[2]=g0.z; gv[3]=g0.w;
            gv[4]=g1.x; gv[5]=g1.y; gv[6]=g1.z; gv[7]=g1.w;
        } else {
#pragma unroll
            for (int j = 0; j < 8; ++j) {
                const int i = s + j;
                const bool ok = i < n_clb;
                av[j] = ok ? a2s[i] : -1;
                gv[j] = ok ? sig[i] : 0;
            }
        }
        unsigned int curw = 0xFFFFFFFFu, curm = 0u;
#pragma unroll
        for (int j = 0; j < 8; ++j) {
            const int site = av[j];
            if (gv[j] > 0 && site >= siteBase && site < siteEnd) {
                const unsigned int u = (unsigned int)(site - siteBase);
                const unsigned int w = u >> 5;
                const unsigned int m = 1u << (u & 31u);
                if (w == curw) curm |= m;
                else { if (curm) atomicOr(&lbm[curw], curm); curw = w; curm = m; }
            }
        }
        if (curm) atomicOr(&lbm[curw], curm);
    }

    __syncthreads();

    // probe: slice_sites[p0..p1) -> rem/avail[p0..p1)
    int i0 = (p0 + 3) & ~3;
    int i1 = p1 & ~3;
    if (i1 < i0) i1 = i0;

    for (int q = (i0 >> 2) + threadIdx.x; q < (i1 >> 2); q += BLOCK) {
        v4i s = __builtin_nontemporal_load((const v4i*)ss + q);
        v4f f = __builtin_nontemporal_load((const v4f*)sc + q);
        v4f r, a;
#pragma unroll
        for (int j = 0; j < 4; ++j) {
            const unsigned int u   = (unsigned int)(s[j] - siteBase);
            const unsigned int bit = (lbm[u >> 5] >> (u & 31u)) & 1u;
            r[j] = bit ? 0.0f : 1.0f;
            a[j] = bit ? 0.0f : f[j];
        }
        __builtin_nontemporal_store(r, (v4f*)rem + q);
        __builtin_nontemporal_store(a, (v4f*)avail + q);
    }
    for (int i = p0 + threadIdx.x; i < min(i0, p1); i += BLOCK) {
        const unsigned int u   = (unsigned int)(ss[i] - siteBase);
        const unsigned int bit = (lbm[u >> 5] >> (u & 31u)) & 1u;
        rem[i]   = bit ? 0.0f : 1.0f;
        avail[i] = bit ? 0.0f : sc[i];
    }
    for (int i = max(i1, p0) + threadIdx.x; i < p1; i += BLOCK) {
        const unsigned int u   = (unsigned int)(ss[i] - siteBase);
        const unsigned int bit = (lbm[u >> 5] >> (u & 31u)) & 1u;
        rem[i]   = bit ? 0.0f : 1.0f;
        avail[i] = bit ? 0.0f : sc[i];
    }
}

// ---- single cooperative kernel ---------------------------------------------
__global__ __launch_bounds__(BLOCK) void coop_kernel(
    const int*   __restrict__ ss,
    const int*   __restrict__ sig,
    const int*   __restrict__ a2s,
    const float* __restrict__ sc,
    int*         __restrict__ eb,
    int*         __restrict__ pb,
    float*       __restrict__ rem,
    float*       __restrict__ avail,
    int n_slice, int n_clb)
{
    __shared__ unsigned int lbm[WORDS_PER_BLOCK];

    const int t0 = blockIdx.x * BLOCK + threadIdx.x;
    const int NT = GRID * BLOCK;
    for (int t = t0; t * 4 < n_slice; t += NT) transitions(ss,  pb, n_slice, t);
    for (int t = t0; t * 4 < n_clb;  t += NT) transitions(a2s, eb, n_clb,  t);

    for (int w = threadIdx.x; w < WORDS_PER_BLOCK; w += BLOCK) lbm[w] = 0u;

    cg::this_grid().sync();   // device-scope: boundary stores visible cross-XCD

    const int g = blockIdx.x;
    const int e0 = __hip_atomic_load(&eb[g],     __ATOMIC_RELAXED, __HIP_MEMORY_SCOPE_AGENT);
    const int e1 = __hip_atomic_load(&eb[g + 1], __ATOMIC_RELAXED, __HIP_MEMORY_SCOPE_AGENT);
    const int p0 = __hip_atomic_load(&pb[g],     __ATOMIC_RELAXED, __HIP_MEMORY_SCOPE_AGENT);
    const int p1 = __hip_atomic_load(&pb[g + 1], __ATOMIC_RELAXED, __HIP_MEMORY_SCOPE_AGENT);

    mark_and_probe(ss, sig, a2s, sc, lbm, rem, avail,
                   e0, e1, p0, p1, g * SITES_PER_BLOCK, n_clb);
}

// ---- R8 fallback path (if cooperative launch is refused) -------------------
__global__ __launch_bounds__(BLOCK) void bounds_kernel(
    const int* __restrict__ ss, const int* __restrict__ a2s,
    int* __restrict__ pb, int* __restrict__ eb, int n_slice, int n_clb)
{
    const int t = blockIdx.x * BLOCK + threadIdx.x;
    transitions(ss,  pb, n_slice, t);
    transitions(a2s, eb, n_clb,  t);
}

__global__ __launch_bounds__(BLOCK) void fused_kernel(
    const int*   __restrict__ ss,
    const int*   __restrict__ sig,
    const int*   __restrict__ a2s,
    const float* __restrict__ sc,
    const int*   __restrict__ eb,
    const int*   __restrict__ pb,
    float*       __restrict__ rem,
    float*       __restrict__ avail,
    int n_clb)
{
    __shared__ unsigned int lbm[WORDS_PER_BLOCK];
    const int g = blockIdx.x;
    for (int w = threadIdx.x; w < WORDS_PER_BLOCK; w += BLOCK) lbm[w] = 0u;
    const int e0 = eb[g], e1 = eb[g + 1];
    const int p0 = pb[g], p1 = pb[g + 1];
    __syncthreads();
    mark_and_probe(ss, sig, a2s, sc, lbm, rem, avail,
                   e0, e1, p0, p1, g * SITES_PER_BLOCK, n_clb);
}

extern "C" void kernel_launch(void* const* d_in, const int* in_sizes, int n_in,
                              void* d_out, int out_size, void* d_ws, size_t ws_size,
                              hipStream_t stream) {
    const int*   ss  = (const int*)d_in[0];
    const int*   sig = (const int*)d_in[1];
    const int*   a2s = (const int*)d_in[2];
    const float* sc  = (const float*)d_in[3];
    int n_slice = in_sizes[0];
    int n_clb   = in_sizes[1];

    int* eb = (int*)d_ws;          // GRID+1 ints
    int* pb = eb + (GRID + 1);     // GRID+1 ints

    float* rem   = (float*)d_out;
    float* avail = rem + n_slice;

    void* args[] = { (void*)&ss, (void*)&sig, (void*)&a2s, (void*)&sc,
                     (void*)&eb, (void*)&pb, (void*)&rem, (void*)&avail,
                     (void*)&n_slice, (void*)&n_clb };
    hipError_t err = hipLaunchCooperativeKernel(
        reinterpret_cast<const void*>(&coop_kernel),
        dim3(GRID), dim3(BLOCK), args, 0, stream);

    if (err != hipSuccess) {
        // Fallback: proven R8 two-kernel path.
        const int n_max = n_slice > n_clb ? n_slice : n_clb;
        const int tblocks = (n_max / 4 + BLOCK - 1) / BLOCK + 1;
        bounds_kernel<<<tblocks, BLOCK, 0, stream>>>(ss, a2s, pb, eb, n_slice, n_clb);
        fused_kernel<<<GRID, BLOCK, 0, stream>>>(ss, sig, a2s, sc, eb, pb,
                                                 rem, avail, n_clb);
    }
}

// Round 10
// 144.730 us; speedup vs baseline: 2.6403x; 2.6403x over previous
//
#include <hip/hip_runtime.h>

// Three lean kernels over a 1 MiB global bitmap (site ids in [0, 2^23)):
//  K1 bounds: streaming bin-transition scan of sorted addr2site_map -> eb[2049]
//             (coalesced vec4, no dependent-load chains; reads 24 MB only).
//  K2 mark:   bin g builds its 128-word LDS bitmap from a2s[eb[g]..eb[g+1])
//             where sig>0 (register-merged LDS atomics), then stores its
//             disjoint 512 B slice to the global bitmap. Full coverage ->
//             no zero pass, no global atomics.
//  K3 probe:  index-partitioned (one thread per vec4, perfectly balanced, no
//             boundary table), probes cache-resident bitmap, NT streams out.

typedef int   v4i __attribute__((ext_vector_type(4)));
typedef float v4f __attribute__((ext_vector_type(4)));

static constexpr int WORDS_PER_BIN = 128;            // 512 B bitmap slice
static constexpr int SITES_PER_BIN = 4096;           // = 2^BIN_SHIFT
static constexpr int BIN_SHIFT     = 12;
static constexpr int NBINS         = 2048;
static constexpr int BLOCK         = 256;

// ---- K1: boundaries of a2s by bin transitions ------------------------------
__global__ __launch_bounds__(BLOCK) void bounds_kernel(
    const int* __restrict__ a2s, int* __restrict__ eb, int n_clb)
{
    const int t = blockIdx.x * BLOCK + threadIdx.x;
    const int s = t * 4;
    if (s >= n_clb) return;
    int v[4];
    int cnt;
    if (s + 4 <= n_clb) {
        v4i a = __builtin_nontemporal_load((const v4i*)(a2s + s));
        v[0] = a.x; v[1] = a.y; v[2] = a.z; v[3] = a.w;
        cnt = 4;
    } else {
        cnt = n_clb - s;
        for (int j = 0; j < cnt; ++j) v[j] = a2s[s + j];
    }
    int pbin = (s == 0) ? -1 : (a2s[s - 1] >> BIN_SHIFT);  // line is in L1
    for (int j = 0; j < cnt; ++j) {
        const int i = s + j;
        const int cbin = v[j] >> BIN_SHIFT;
        for (int b = pbin + 1; b <= cbin; ++b) eb[b] = i;   // ~1 write / 2929 elems
        if (i == n_clb - 1)
            for (int b = cbin + 1; b <= NBINS; ++b) eb[b] = n_clb;
        pbin = cbin;
    }
}

// ---- K2: per-bin mark -> disjoint global bitmap slice ----------------------
__global__ __launch_bounds__(BLOCK) void mark_kernel(
    const int* __restrict__ sig, const int* __restrict__ a2s,
    const int* __restrict__ eb, unsigned int* __restrict__ bm, int n_clb)
{
    __shared__ unsigned int lbm[WORDS_PER_BIN];

    const int g        = blockIdx.x;
    const int siteBase = g * SITES_PER_BIN;
    const int siteEnd  = siteBase + SITES_PER_BIN;

    if (threadIdx.x < WORDS_PER_BIN) lbm[threadIdx.x] = 0u;
    const int e0 = eb[g], e1 = eb[g + 1];
    __syncthreads();

    // 8 entries/thread (4 NT vec4 loads in flight). Strays outside the bin's
    // site range fail the range check (they belong to neighbor bins).
    const int mstart = e0 & ~3;
    for (int s = mstart + threadIdx.x * 8; s < e1; s += BLOCK * 8) {
        int av[8], gv[8];
        if (s + 8 <= n_clb) {
            v4i a0 = __builtin_nontemporal_load((const v4i*)(a2s + s));
            v4i a1 = __builtin_nontemporal_load((const v4i*)(a2s + s + 4));
            v4i g0 = __builtin_nontemporal_load((const v4i*)(sig + s));
            v4i g1 = __builtin_nontemporal_load((const v4i*)(sig + s + 4));
            av[0]=a0.x; av[1]=a0.y; av[2]=a0.z; av[3]=a0.w;
            av[4]=a1.x; av[5]=a1.y; av[6]=a1.z; av[7]=a1.w;
            gv[0]=g0.x; gv[1]=g0.y; gv[2]=g0.z; gv[3]=g0.w;
            gv[4]=g1.x; gv[5]=g1.y; gv[6]=g1.z; gv[7]=g1.w;
        } else {
#pragma unroll
            for (int j = 0; j < 8; ++j) {
                const int i = s + j;
                const bool ok = i < n_clb;
                av[j] = ok ? a2s[i] : -1;
                gv[j] = ok ? sig[i] : 0;
            }
        }
        unsigned int curw = 0xFFFFFFFFu, curm = 0u;
#pragma unroll
        for (int j = 0; j < 8; ++j) {
            const int site = av[j];
            if (gv[j] > 0 && site >= siteBase && site < siteEnd) {
                const unsigned int u = (unsigned int)(site - siteBase);
                const unsigned int w = u >> 5;
                const unsigned int m = 1u << (u & 31u);
                if (w == curw) curm |= m;
                else { if (curm) atomicOr(&lbm[curw], curm); curw = w; curm = m; }
            }
        }
        if (curm) atomicOr(&lbm[curw], curm);
    }

    __syncthreads();

    // Disjoint 512 B slice -> regular stores (keep it cache-resident for K3).
    if (threadIdx.x < WORDS_PER_BIN / 4)
        ((v4i*)(bm + g * WORDS_PER_BIN))[threadIdx.x] =
            ((const v4i*)lbm)[threadIdx.x];
}

// ---- K3: index-partitioned probe ------------------------------------------
__global__ __launch_bounds__(BLOCK) void probe_kernel(
    const int* __restrict__ ss, const float* __restrict__ sc,
    const unsigned int* __restrict__ bm,
    float* __restrict__ rem, float* __restrict__ avail, int n4)
{
    const int q = blockIdx.x * BLOCK + threadIdx.x;
    if (q >= n4) return;
    v4i s = __builtin_nontemporal_load((const v4i*)ss + q);
    v4f f = __builtin_nontemporal_load((const v4f*)sc + q);
    v4f r, a;
#pragma unroll
    for (int j = 0; j < 4; ++j) {
        const unsigned int u   = (unsigned int)s[j];
        const unsigned int bit = (bm[u >> 5] >> (u & 31u)) & 1u;
        r[j] = bit ? 0.0f : 1.0f;
        a[j] = bit ? 0.0f : f[j];
    }
    __builtin_nontemporal_store(r, (v4f*)rem + q);
    __builtin_nontemporal_store(a, (v4f*)avail + q);
}

__global__ void probe_tail_kernel(
    const int* __restrict__ ss, const float* __restrict__ sc,
    const unsigned int* __restrict__ bm,
    float* __restrict__ rem, float* __restrict__ avail, int start, int n)
{
    const int i = start + blockIdx.x * blockDim.x + threadIdx.x;
    if (i >= n) return;
    const unsigned int u   = (unsigned int)ss[i];
    const unsigned int bit = (bm[u >> 5] >> (u & 31u)) & 1u;
    rem[i]   = bit ? 0.0f : 1.0f;
    avail[i] = bit ? 0.0f : sc[i];
}

extern "C" void kernel_launch(void* const* d_in, const int* in_sizes, int n_in,
                              void* d_out, int out_size, void* d_ws, size_t ws_size,
                              hipStream_t stream) {
    const int*   ss  = (const int*)d_in[0];
    const int*   sig = (const int*)d_in[1];
    const int*   a2s = (const int*)d_in[2];
    const float* sc  = (const float*)d_in[3];
    const int n_slice = in_sizes[0];
    const int n_clb   = in_sizes[1];

    unsigned int* bm = (unsigned int*)d_ws;                 // 1 MiB bitmap
    int*          eb = (int*)(bm + NBINS * WORDS_PER_BIN);  // 2049 ints

    // K1: boundaries of a2s (24 MB streaming scan)
    const int t1 = (n_clb / 4 + BLOCK - 1) / BLOCK + 1;
    bounds_kernel<<<t1, BLOCK, 0, stream>>>(a2s, eb, n_clb);

    // K2: per-bin mark -> global bitmap (disjoint stores, full coverage)
    mark_kernel<<<NBINS, BLOCK, 0, stream>>>(sig, a2s, eb, bm, n_clb);

    // K3: index-partitioned probe -> outputs
    float* rem   = (float*)d_out;
    float* avail = rem + n_slice;
    const int n4 = n_slice / 4;
    if (n4 > 0)
        probe_kernel<<<(n4 + BLOCK - 1) / BLOCK, BLOCK, 0, stream>>>(
            ss, sc, bm, rem, avail, n4);
    if (n4 * 4 < n_slice)
        probe_tail_kernel<<<1, 64, 0, stream>>>(ss, sc, bm, rem, avail,
                                                n4 * 4, n_slice);
}